// Round 2
// baseline (214.994 us; speedup 1.0000x reference)
//
#include <hip/hip_runtime.h>
#include <math.h>

// Problem constants: B=2, C=O=256, H=W=64, K=33 offsets (D=4 rings).
typedef __attribute__((ext_vector_type(4))) float f4;

__device__ __forceinline__ int iclamp(int x, int lo, int hi) {
    return min(max(x, lo), hi);
}

// Offset tables (order irrelevant: softmax is permutation-invariant).
// k=0:(0,0); rings s=1..4: (-s,-s),(-s,0),(-s,s),(0,-s),(0,s),(s,-s),(s,0),(s,s)
#define DX_TBL {0, -1,-1,-1,0,0,1,1,1, -2,-2,-2,0,0,2,2,2, -3,-3,-3,0,0,3,3,3, -4,-4,-4,0,0,4,4,4}
#define DY_TBL {0, -1,0,1,-1,1,-1,0,1, -2,0,2,-2,2,-2,0,2, -3,0,3,-3,3,-3,0,3, -4,0,4,-4,4,-4,0,4}

// ---------------------------------------------------------------------------
// GEMM: E[b][o][p] = sum_c W[o][c] * F[b][c][p] + bias[o]
// M=256(o), N=4096(p=h*64+w), K=256(c). grid (64 n-tiles, 4 m-tiles, 4 = g*2+b)
// fp32 vector FMA (round 1: numerics-safe; MFMA planned for later rounds).
// ---------------------------------------------------------------------------
__global__ __launch_bounds__(256) void gemm_f32(
    const float* __restrict__ Wf, const float* __restrict__ bf,
    const float* __restrict__ Wg, const float* __restrict__ bg,
    const float* __restrict__ Ft, const float* __restrict__ FtE,
    float* __restrict__ Ef, float* __restrict__ Eg)
{
    __shared__ float AsubT[16][68];  // [k][m] transposed; 68 keeps rows 16B-aligned, conflicts <=2-way
    __shared__ float Bsub[16][68];   // [k][n]

    const int bn = blockIdx.x, bm = blockIdx.y, gb = blockIdx.z;
    const int g = gb >> 1, b = gb & 1;
    const float* Wmat = g ? Wg : Wf;
    const float* bias = g ? bg : bf;
    const float* X = (g ? FtE : Ft) + (size_t)b * 256 * 4096;
    float* E = (g ? Eg : Ef) + (size_t)b * 256 * 4096;

    const int tid = threadIdx.x;
    const int tn = tid & 15, tm = tid >> 4;
    const int m0 = bm * 64, n0 = bn * 64;

    float acc[4][4] = {};

    for (int kk = 0; kk < 256; kk += 16) {
        __syncthreads();
        // stage A tile 64(m) x 16(k), store transposed [k][m]
        for (int p = 0; p < 4; ++p) {
            int r = (tid >> 4) + p * 16;   // m row 0..63
            int c = tid & 15;              // k col 0..15
            AsubT[c][r] = Wmat[(m0 + r) * 256 + kk + c];
        }
        // stage B tile 16(k) x 64(n)
        for (int p = 0; p < 4; ++p) {
            int r = (tid >> 6) + p * 4;    // k row 0..15
            int c = tid & 63;              // n col 0..63
            Bsub[r][c] = X[(kk + r) * 4096 + n0 + c];
        }
        __syncthreads();
        #pragma unroll
        for (int k = 0; k < 16; ++k) {
            f4 a = *(const f4*)&AsubT[k][tm * 4];
            f4 bb = *(const f4*)&Bsub[k][tn * 4];
            #pragma unroll
            for (int i = 0; i < 4; ++i)
                #pragma unroll
                for (int j = 0; j < 4; ++j)
                    acc[i][j] += a[i] * bb[j];
        }
    }

    #pragma unroll
    for (int i = 0; i < 4; ++i) {
        int o = m0 + tm * 4 + i;
        float bv = bias[o];
        f4 v = { acc[i][0] + bv, acc[i][1] + bv, acc[i][2] + bv, acc[i][3] + bv };
        *(f4*)&E[(size_t)o * 4096 + n0 + tn * 4] = v;
    }
}

// ---------------------------------------------------------------------------
// Fused local attention: per pixel, aff[k] = sum_c Eg[c]*Ef_n[c,k]; softmax
// over 33 offsets (-inf for out-of-bounds); out[c] = sum_k w[k]*Ft_n[c,k].
// grid (4 w-tiles of 16, 64 h, 2 b), block 128 = (16 w) x (8 k-groups).
// LDS stages 10 halo rows (9 shifted Ef rows + 1 Eg row) per channel chunk.
// ---------------------------------------------------------------------------
__global__ __launch_bounds__(128) void attn(
    const float* __restrict__ Ef, const float* __restrict__ Eg,
    const float* __restrict__ Ft, float* __restrict__ out)
{
    constexpr int DX[33] = DX_TBL;
    constexpr int DY[33] = DY_TBL;

    __shared__ float Lbuf[2560];      // [dxi 0..9][i 0..7][col 0..31]; rows of 32 (pow2 indexing)
    __shared__ float aff[33][16];     // aff then softmax weights, per (k, w)

    const int wt = blockIdx.x, h = blockIdx.y, b = blockIdx.z;
    const int w0 = wt * 16;
    const int tid = threadIdx.x;
    const int w = tid & 15, kg = tid >> 4;   // kg 0..7; thread owns k = kg + 8j
    const size_t plane = (size_t)b * 256 * 4096;
    const float* EfB = Ef + plane;
    const float* EgB = Eg + plane;
    const float* FtB = Ft + plane;
    float* outB = out + plane;

    // per-thread compile-time-resolved offset slots: k = kg + 8*j, j=0..4 (j=4 only kg==0)
    float acc[5] = {0.f, 0.f, 0.f, 0.f, 0.f};
    int loff[5];
    bool vld[5];
    #pragma unroll
    for (int k = 0; k < 33; ++k) {
        if ((k & 7) == kg) {          // k&7 compile-time, kg runtime-uniform per 16-lane group
            const int dx = DX[k], dy = DY[k];   // immediates
            const int j = k >> 3;
            loff[j] = (dx + 4) * 256 + 4 + w + dy;
            vld[j] = ((unsigned)(h + dx) < 64u) && ((unsigned)(w0 + w + dy) < 64u);
        }
    }
    // staging column: idx&31 == tid&31 (128 % 32 == 0)
    const int wsrc = iclamp(w0 - 4 + (tid & 31), 0, 63);

    // ---- phase 1: accumulate aff over all 256 channels, chunks of 8 ----
    for (int cc = 0; cc < 256; cc += 8) {
        __syncthreads();
        for (int it = 0; it < 20; ++it) {      // 2560 elems / 128 threads
            int idx = it * 128 + tid;
            int row = idx >> 5;                // 0..79
            int dxi = row >> 3, i = row & 7;
            int c = cc + i;
            const float* src;
            int hr;
            if (dxi < 9) { hr = iclamp(h + dxi - 4, 0, 63); src = EfB; }
            else         { hr = h;                          src = EgB; }
            Lbuf[idx] = src[(c * 64 + hr) * 64 + wsrc];
        }
        __syncthreads();
        #pragma unroll
        for (int i = 0; i < 8; ++i) {
            float eg = Lbuf[(72 + i) * 32 + 4 + w];
            int ib = i * 32;
            #pragma unroll
            for (int j = 0; j < 4; ++j)
                acc[j] += eg * Lbuf[loff[j] + ib];
            if (kg == 0)
                acc[4] += eg * Lbuf[loff[4] + ib];
        }
    }

    #pragma unroll
    for (int j = 0; j < 4; ++j)
        aff[kg + 8 * j][w] = vld[j] ? acc[j] : -INFINITY;
    if (kg == 0)
        aff[32][w] = vld[4] ? acc[4] : -INFINITY;
    __syncthreads();

    // ---- phase 2: softmax over k per w (k=0 always valid -> m finite) ----
    if (tid < 16) {
        float m = -INFINITY;
        for (int k = 0; k < 33; ++k) m = fmaxf(m, aff[k][tid]);
        float s = 0.f;
        for (int k = 0; k < 33; ++k) s += __expf(aff[k][tid] - m);
        float inv = 1.f / s;
        for (int k = 0; k < 33; ++k) aff[k][tid] = __expf(aff[k][tid] - m) * inv;
    }
    __syncthreads();

    // ---- phase 3: out[c] = sum_k wgt[k] * Ft_n[c,k]; thread owns c = cc+kg ----
    const int cg = kg;
    const int cbase = cg * 32 + 4 + w;
    for (int cc = 0; cc < 256; cc += 8) {
        __syncthreads();
        for (int it = 0; it < 18; ++it) {      // 9*8*32 = 2304 elems exactly
            int idx = it * 128 + tid;
            int row = idx >> 5;                // 0..71
            int dxi = row >> 3, i = row & 7;
            int c = cc + i;
            int hr = iclamp(h + dxi - 4, 0, 63);
            Lbuf[idx] = FtB[(c * 64 + hr) * 64 + wsrc];
        }
        __syncthreads();
        int c = cc + cg;
        float o = 0.f;
        #pragma unroll
        for (int k = 0; k < 33; ++k)
            o += aff[k][w] * Lbuf[(DX[k] + 4) * 256 + cbase + DY[k]];  // wgt==0 masks invalid k
        outB[(c * 64 + h) * 64 + w0 + w] = o;
    }
}

// ---------------------------------------------------------------------------
extern "C" void kernel_launch(void* const* d_in, const int* in_sizes, int n_in,
                              void* d_out, int out_size, void* d_ws, size_t ws_size,
                              hipStream_t stream) {
    const float* Ft  = (const float*)d_in[0];
    const float* FtE = (const float*)d_in[1];
    const float* Wf  = (const float*)d_in[2];
    const float* bf  = (const float*)d_in[3];
    const float* Wg  = (const float*)d_in[4];
    const float* bg  = (const float*)d_in[5];
    float* out = (float*)d_out;

    // workspace: Ef (8 MB) + Eg (8 MB) fp32, layout [b][o][h*64+w]
    float* Ef = (float*)d_ws;
    float* Eg = Ef + (size_t)2 * 256 * 4096;

    hipLaunchKernelGGL(gemm_f32, dim3(64, 4, 4), dim3(256), 0, stream,
                       Wf, bf, Wg, bg, Ft, FtE, Ef, Eg);
    hipLaunchKernelGGL(attn, dim3(4, 64, 2), dim3(128), 0, stream,
                       Ef, Eg, Ft, out);
}